// Round 1
// baseline (371.280 us; speedup 1.0000x reference)
//
#include <hip/hip_runtime.h>

// Problem constants
#define H_ 96
#define W_ 96
#define HW 9216        // 96*96
#define C_ 64
#define OUTC 64
#define NPTS 9         // N = KS*KS
#define NCH 18         // 2*N offset channels
#define B_ 8
#define NPIX 73728     // B*H*W

// ---------------- Kernel A: offset field (3x3 conv, pad 1) ----------------
// offs[b][ch][i][j] = b_off[ch] + sum_{c,u,v} x[b][c][i+u-1][j+v-1] * w_off[ch][c][u][v]
__global__ __launch_bounds__(256) void offs_kernel(
    const float* __restrict__ x, const float* __restrict__ w_off,
    const float* __restrict__ b_off, float* __restrict__ offs)
{
    __shared__ float sw[NCH * C_ * 9];   // 10368 floats = 41.5 KB
    int t = threadIdx.x;
    for (int idx = t; idx < NCH * C_ * 9; idx += 256) sw[idx] = w_off[idx];
    __syncthreads();

    int pixel = blockIdx.x * 256 + t;    // 288 blocks * 256 = 73728 exactly
    int b   = pixel / HW;
    int rem = pixel - b * HW;
    int i   = rem / W_;
    int j   = rem - i * W_;

    float acc[NCH];
#pragma unroll
    for (int ch = 0; ch < NCH; ++ch) acc[ch] = b_off[ch];

    const float* xb = x + b * C_ * HW;
    for (int c = 0; c < C_; ++c) {
        const float* xp = xb + c * HW;
        float v[9];
#pragma unroll
        for (int u = 0; u < 3; ++u)
#pragma unroll
            for (int vv = 0; vv < 3; ++vv) {
                int ii = i + u - 1, jj = j + vv - 1;
                bool ok = (ii >= 0) & (ii < H_) & (jj >= 0) & (jj < W_);
                v[u * 3 + vv] = ok ? xp[ii * W_ + jj] : 0.0f;
            }
        const float* swc = &sw[c * 9];
#pragma unroll
        for (int ch = 0; ch < NCH; ++ch) {
#pragma unroll
            for (int uv = 0; uv < 9; ++uv)
                acc[ch] += v[uv] * swc[ch * (C_ * 9) + uv];
        }
    }
    float* op = offs + b * NCH * HW + rem;
#pragma unroll
    for (int ch = 0; ch < NCH; ++ch) op[ch * HW] = acc[ch];
}

// ---------------- Kernel T: transpose w_ker into wk_t[k][oc], k = n*64 + c ----------------
__global__ __launch_bounds__(256) void wk_transpose(
    const float* __restrict__ w_ker, float* __restrict__ wk_t)
{
    int idx = blockIdx.x * 256 + threadIdx.x;  // 144*256 = 36864 exactly
    int oc = idx & 63;
    int kc = idx >> 6;       // n*64 + c
    int c  = kc & 63;
    int n  = kc >> 6;
    wk_t[idx] = w_ker[(oc * C_ + c) * 9 + n];
}

// ---------------- Kernel B: fused bilinear sample + GEMM ----------------
// out[b][oc][i][j] = b_ker[oc] + sum_{n,c} wk_t[n*64+c][oc] * bilinear(x[b][c], i+pnx+offx, j+pny+offy)
__global__ __launch_bounds__(128) void deform_gemm(
    const float* __restrict__ x, const float* __restrict__ offs,
    const float* __restrict__ wk_t, const float* __restrict__ b_ker,
    float* __restrict__ out)
{
    __shared__ float s_val[32 * 128];  // [c_local][p]  16 KB
    __shared__ float s_wk [32 * 64];   // [c_local][oc]  8 KB

    int t    = threadIdx.x;
    int base = blockIdx.x * 128;       // 576 blocks; 9216 % 128 == 0 so b uniform per block
    int b    = base / HW;
    int rem0 = base - b * HW;
    int pix  = rem0 + t;
    int i    = pix / W_;
    int j    = pix - i * W_;

    const float* xb = x + b * C_ * HW;

    float acc[8][8];
#pragma unroll
    for (int a = 0; a < 8; ++a)
#pragma unroll
        for (int bb = 0; bb < 8; ++bb) acc[a][bb] = 0.0f;

    for (int n = 0; n < NPTS; ++n) {
        // sampling coords for my pixel (p == t), reused over all 64 channels
        float offx = offs[(b * NCH + n) * HW + pix];
        float offy = offs[(b * NCH + NPTS + n) * HW + pix];
        float px = (float)(i + n / 3 - 1) + offx;
        float py = (float)(j + n % 3 - 1) + offy;
        float x0f = floorf(px), y0f = floorf(py);
        float lx = px - x0f, ly = py - y0f;
        int xi = (int)x0f, yi = (int)y0f;

        int a4[4]; float w4[4];
        float wx[2] = {1.0f - lx, lx};
        float wy[2] = {1.0f - ly, ly};
#pragma unroll
        for (int q = 0; q < 4; ++q) {
            int cx = xi + (q & 1);           // row
            int cy = yi + (q >> 1);          // col
            bool ok = (cx >= 0) & (cx < H_) & (cy >= 0) & (cy < W_);
            int ax = min(max(cx, 0), H_ - 1);
            int ay = min(max(cy, 0), W_ - 1);
            a4[q] = ax * W_ + ay;
            w4[q] = ok ? wx[q & 1] * wy[q >> 1] : 0.0f;
        }

        for (int ch = 0; ch < 2; ++ch) {
            __syncthreads();   // previous GEMM finished reading s_val/s_wk
            // stage 32x64 weight chunk (coalesced)
            const float* wsrc = wk_t + (n * 64 + ch * 32) * 64;
#pragma unroll
            for (int r = 0; r < 16; ++r) s_wk[r * 128 + t] = wsrc[r * 128 + t];
            // gather: lane = pixel, loop channels
            const float* xc = xb + (ch * 32) * HW;
#pragma unroll 4
            for (int c = 0; c < 32; ++c) {
                const float* xp = xc + c * HW;
                float v = w4[0] * xp[a4[0]] + w4[1] * xp[a4[1]]
                        + w4[2] * xp[a4[2]] + w4[3] * xp[a4[3]];
                s_val[c * 128 + t] = v;
            }
            __syncthreads();
            // GEMM: per-thread 8 pixels x 8 ocs
            int ocg = t & 7, pg = t >> 3;
#pragma unroll 2
            for (int k = 0; k < 32; ++k) {
                float4 s0 = *(const float4*)&s_val[k * 128 + pg * 8];
                float4 s1 = *(const float4*)&s_val[k * 128 + pg * 8 + 4];
                float4 w0 = *(const float4*)&s_wk [k * 64 + ocg * 8];
                float4 w1 = *(const float4*)&s_wk [k * 64 + ocg * 8 + 4];
                float sv[8] = {s0.x, s0.y, s0.z, s0.w, s1.x, s1.y, s1.z, s1.w};
                float wv[8] = {w0.x, w0.y, w0.z, w0.w, w1.x, w1.y, w1.z, w1.w};
#pragma unroll
                for (int pp = 0; pp < 8; ++pp)
#pragma unroll
                    for (int cc = 0; cc < 8; ++cc)
                        acc[pp][cc] += sv[pp] * wv[cc];
            }
        }
    }

    // epilogue: vectorized stores, 8 oc x 2 float4 per thread
    int ocg = t & 7, pg = t >> 3;
#pragma unroll
    for (int cc = 0; cc < 8; ++cc) {
        int oc = ocg * 8 + cc;
        float bk = b_ker[oc];
        float* op = out + (b * OUTC + oc) * HW + rem0 + pg * 8;
        float4 v0 = make_float4(acc[0][cc] + bk, acc[1][cc] + bk,
                                acc[2][cc] + bk, acc[3][cc] + bk);
        float4 v1 = make_float4(acc[4][cc] + bk, acc[5][cc] + bk,
                                acc[6][cc] + bk, acc[7][cc] + bk);
        *(float4*)&op[0] = v0;
        *(float4*)&op[4] = v1;
    }
}

extern "C" void kernel_launch(void* const* d_in, const int* in_sizes, int n_in,
                              void* d_out, int out_size, void* d_ws, size_t ws_size,
                              hipStream_t stream) {
    const float* x     = (const float*)d_in[0];
    const float* w_off = (const float*)d_in[1];
    const float* b_off = (const float*)d_in[2];
    const float* w_ker = (const float*)d_in[3];
    const float* b_ker = (const float*)d_in[4];
    float* out = (float*)d_out;

    float* ws   = (float*)d_ws;
    float* offs = ws;                 // 8*18*9216 = 1,327,104 floats (5.3 MB)
    float* wk_t = ws + 1327104;       // 36,864 floats

    offs_kernel <<<NPIX / 256, 256, 0, stream>>>(x, w_off, b_off, offs);
    wk_transpose<<<144,        256, 0, stream>>>(w_ker, wk_t);
    deform_gemm <<<NPIX / 128, 128, 0, stream>>>(x, offs, wk_t, b_ker, out);
}